// Round 14
// baseline (308.101 us; speedup 1.0000x reference)
//
#include <hip/hip_runtime.h>
#include <stdint.h>

// ---------------------------------------------------------------------------
// VarianceMaximizationCovarianceMinimizationLoss on MI355X
//   features [65536,2,256] fp32, labels [65536] int32 -> scalar fp32 loss
// Round 14: round-13 structure with the k_scatter LDS indexing bug fixed
//   (sumbuf strides were inconsistent -> OOB LDS -> nondeterministic output).
//   k_rank    : inverse permutation rank[row] = sorted position
//   k_scatter : LINEAR coalesced X read -> bf16 row-major sorted write
//               (rank-directed, 512B/row) + fused class column sums
//   k_gram    : per-(class, quadrant, g) 128x128 Gram from sorted bf16:
//               contiguous loads, proven transposed+swizzled LDS staging,
//               8-wave WGs, acc=32 AGPR, G groups sized from ws_size.
//   k_loss    : sum G slabs -> cov -> std + offdiag^2 -> scalar
// ---------------------------------------------------------------------------

#define NCLS  8
#define D     256
#define CHUNK 1024
#define SEG   256
#define EPSF  1e-4f
#define QLEN  16384      // 128x128 slab elements

typedef __bf16 bf16x8 __attribute__((ext_vector_type(8)));
typedef float  f32x4  __attribute__((ext_vector_type(4)));

__device__ __forceinline__ unsigned short f2bf(float f) {
    unsigned int x = __float_as_uint(f);
    x += 0x7fffu + ((x >> 16) & 1u);      // round-to-nearest-even
    return (unsigned short)(x >> 16);
}
__device__ __forceinline__ float bf2f(unsigned short u) {
    return __uint_as_float(((unsigned int)u) << 16);
}
// transposed + XOR-swizzled LDS write of 4 k-rows x 8 cols (validated
// conflict-free rounds 3-12: SQ_LDS_BANK_CONFLICT = 0)
__device__ __forceinline__ void st_tile(unsigned char* lds, const uint4* R,
                                        int kblk, int cblkg) {
    #pragma unroll
    for (int cc = 0; cc < 8; ++cc) {
        int wd = cc >> 1;
        int sh = (cc & 1) * 16;
        unsigned int e0 = (((const unsigned int*)&R[0])[wd] >> sh) & 0xffffu;
        unsigned int e1 = (((const unsigned int*)&R[1])[wd] >> sh) & 0xffffu;
        unsigned int e2 = (((const unsigned int*)&R[2])[wd] >> sh) & 0xffffu;
        unsigned int e3 = (((const unsigned int*)&R[3])[wd] >> sh) & 0xffffu;
        int ccol = cblkg * 8 + cc;
        int byt = ccol * 128 + ((kblk * 8) ^ (cc << 4));
        *(uint2*)(lds + byt) = make_uint2(e0 | (e1 << 16), e2 | (e3 << 16));
    }
}

// ---- k1a: histogram -------------------------------------------------------
__global__ void k_hist(const int* __restrict__ labels, int nlab, int vfac,
                       int* __restrict__ counts) {
    __shared__ int lc[NCLS];
    int t = threadIdx.x;
    if (t < NCLS) lc[t] = 0;
    __syncthreads();
    for (int i = blockIdx.x * blockDim.x + t; i < nlab; i += gridDim.x * blockDim.x)
        atomicAdd(&lc[labels[i] & 7], vfac);
    __syncthreads();
    if (t < NCLS && lc[t]) atomicAdd(&counts[t], lc[t]);
}

// ---- k1b: offsets + cursors ----------------------------------------------
__global__ void k_offsets(const int* __restrict__ counts,
                          int* __restrict__ offsets, int* __restrict__ cursor) {
    if (threadIdx.x == 0) {
        int acc = 0;
        for (int c = 0; c < NCLS; ++c) { offsets[c] = acc; cursor[c] = acc; acc += counts[c]; }
    }
}

// ---- k2: inverse permutation rank[row] = sorted position ------------------
__global__ __launch_bounds__(256) void k_rank(
    const int* __restrict__ labels, int nrows, int vfac,
    int* __restrict__ cursor, int* __restrict__ rank)
{
    __shared__ int lcnt[NCLS], lbase[NCLS];
    int t = threadIdx.x;
    int row = blockIdx.x * SEG + t;
    if (t < NCLS) lcnt[t] = 0;
    __syncthreads();
    int c = 0, rk = 0;
    bool ok = (row < nrows);
    if (ok) {
        c = labels[row / vfac] & 7;
        rk = atomicAdd(&lcnt[c], 1);
    }
    __syncthreads();
    if (t < NCLS) lbase[t] = lcnt[t] ? atomicAdd(&cursor[t], lcnt[t]) : 0;
    __syncthreads();
    if (ok) rank[row] = lbase[c] + rk;
}

// ---- k3: linear-read scatter to sorted bf16 + fused class sums ------------
// WG = 512 threads (8 waves). Wave w handles rows r0w..r0w+63:
//   lane preloads rank/label for its row; per row i: __shfl broadcast of
//   dest+class, coalesced f32x4 X read (lane*4 features), LDS class-sum
//   accumulate in [w][c][e][lane] layout (stride 64/e, 256/class, 2048/wave
//   -- CONSISTENT alloc/index/reduce, fixes round-13 OOB), bf16 pack,
//   8B store into sorted[dest] (512B contiguous per row).
__global__ __launch_bounds__(512) void k_scatter(
    const float* __restrict__ X, const int* __restrict__ labels,
    const int* __restrict__ rank, int nrows, int vfac,
    unsigned short* __restrict__ sorted, float* __restrict__ gsums)
{
    __shared__ float sumbuf[8][NCLS][4][64];        // 64 KB
    int t = threadIdx.x;
    int w = t >> 6, lane = t & 63;

    for (int i = t; i < 8 * NCLS * 4 * 64; i += 512)
        (&sumbuf[0][0][0][0])[i] = 0.f;
    __syncthreads();

    int r0w = blockIdx.x * 512 + w * 64;
    if (r0w < nrows) {
        int myrow = r0w + lane;
        int rankv = (myrow < nrows) ? rank[myrow] : 0;
        int labv  = (myrow < nrows) ? (labels[myrow / vfac] & 7) : 0;
        int nloc = min(64, nrows - r0w);
        for (int i = 0; i < nloc; ++i) {
            int dest = __shfl(rankv, i, 64);
            int c    = __shfl(labv, i, 64);
            f32x4 v = *(const f32x4*)(X + ((size_t)(r0w + i) << 8) + lane * 4);
            float* sc = &sumbuf[w][c][0][lane];     // +64 per e
            sc[0]   += v[0];
            sc[64]  += v[1];
            sc[128] += v[2];
            sc[192] += v[3];
            ushort4 o;
            o.x = f2bf(v[0]); o.y = f2bf(v[1]); o.z = f2bf(v[2]); o.w = f2bf(v[3]);
            *(ushort4*)(sorted + ((size_t)dest << 8) + lane * 4) = o;
        }
    }
    __syncthreads();

    // reduce the 8 wave regions (flat stride 2048) and emit atomics
    for (int s = t; s < NCLS * 4 * 64; s += 512) {
        float val = 0.f;
        #pragma unroll
        for (int wb = 0; wb < 8; ++wb)
            val += (&sumbuf[0][0][0][0])[wb * (NCLS * 4 * 64) + s];
        if (val != 0.f) {
            int c  = s >> 8;            // /256
            int e  = (s >> 6) & 3;
            int ln = s & 63;
            atomicAdd(&gsums[c * D + ln * 4 + e], val);
        }
    }
}

// ---- k4: per-(class, quadrant, g) 128x128 Gram ----------------------------
// WG = 512 threads (8 waves as 2x4: wave = 64 rows x 32 cols, acc 4x2 = 32).
// Quadrants: q0 = [0:128]x[0:128], q1 = [128:]x[128:], q2 = [0:128]x[128:].
// LDS: 64 k-rows x {128 (q0/q1) | 256 (q2)} feats, transposed+swizzled.
// Staging thread (kblk=t&15, cblk0=t>>4): 4 contiguous 16B bf16 loads.
// WG (c,q,g) accumulates chunks m = g, g+G, ... in AGPRs.
__global__ __launch_bounds__(512) void k_gram(
    const unsigned short* __restrict__ sorted,
    const int* __restrict__ counts, const int* __restrict__ offsets,
    unsigned short* __restrict__ part, int G)
{
    __shared__ __align__(16) unsigned char lds[64 * 256 * 2];   // 32 KB

    int t = threadIdx.x;
    int lane = t & 63;
    int w = t >> 6;
    int wr = w >> 2, wc = w & 3;
    int kblk = t & 15;
    int cblk0 = t >> 4;          // 0..31

    int blk = blockIdx.x;
    int c = blk / (3 * G);
    int rem = blk - c * (3 * G);
    int q = rem / G;
    int g = rem - q * G;

    int base0 = offsets[c];
    int n = counts[c];
    int nch = (n + CHUNK - 1) / CHUNK;

    int np   = (q == 2) ? 32 : 16;      // staged 8-col panels
    int colb = (q == 1) ? 128 : 0;      // global feature base of panel 0
    int bbase = (q == 2) ? 128 : 0;     // B-fragment LDS col base

    f32x4 acc[4][2];
    #pragma unroll
    for (int i = 0; i < 4; ++i)
        #pragma unroll
        for (int j = 0; j < 2; ++j)
            #pragma unroll
            for (int r = 0; r < 4; ++r) acc[i][j][r] = 0.f;

    bool st = (cblk0 < np);
    const uint4 zq = make_uint4(0u, 0u, 0u, 0u);

    for (int m = g; m < nch; m += G) {
        int base = base0 + m * CHUNK;
        int rows = min(CHUNK, n - m * CHUNK);
        int ntiles = (rows + 63) >> 6;
        for (int kt = 0; kt < ntiles; ++kt) {
            uint4 R[4];
            if (st) {
                #pragma unroll
                for (int j = 0; j < 4; ++j) {
                    int r = kt * 64 + kblk * 4 + j;
                    R[j] = (r < rows)
                        ? *(const uint4*)(sorted + (((size_t)(base + r)) << 8)
                                          + colb + cblk0 * 8)
                        : zq;
                }
            }
            __syncthreads();            // previous tile's LDS reads done
            if (st) st_tile(lds, R, kblk, cblk0);
            __syncthreads();            // staging visible
            #pragma unroll
            for (int ks = 0; ks < 2; ++ks) {
                int kb2 = ks * 64 + ((lane >> 4) << 4);
                int swz = (lane & 7) << 4;
                bf16x8 bfr[2];
                #pragma unroll
                for (int tj = 0; tj < 2; ++tj) {
                    int ccol = bbase + wc * 32 + tj * 16 + (lane & 15);
                    bfr[tj] = __builtin_bit_cast(bf16x8,
                        *(const uint4*)(lds + ccol * 128 + (kb2 ^ swz)));
                }
                #pragma unroll
                for (int ti = 0; ti < 4; ++ti) {
                    int ccol = wr * 64 + ti * 16 + (lane & 15);
                    bf16x8 af = __builtin_bit_cast(bf16x8,
                        *(const uint4*)(lds + ccol * 128 + (kb2 ^ swz)));
                    #pragma unroll
                    for (int tj = 0; tj < 2; ++tj)
                        acc[ti][tj] = __builtin_amdgcn_mfma_f32_16x16x32_bf16(
                            af, bfr[tj], acc[ti][tj], 0, 0, 0);
                }
            }
        }
    }

    // flush 128x128 bf16 slab (C/D: col=lane&15, row=(lane>>4)*4+r)
    unsigned short* dst = part + (size_t)blk * QLEN;
    #pragma unroll
    for (int ti = 0; ti < 4; ++ti) {
        int row0 = wr * 64 + ti * 16 + ((lane >> 4) << 2);
        #pragma unroll
        for (int tj = 0; tj < 2; ++tj) {
            int col = wc * 32 + tj * 16 + (lane & 15);
            #pragma unroll
            for (int r = 0; r < 4; ++r)
                dst[(row0 + r) * 128 + col] = f2bf(acc[ti][tj][r]);
        }
    }
}

// ---- k5: loss epilogue from (c,q,g) bf16 slabs ----------------------------
// full-matrix sums = q0 + q1 + 2*q2 (symmetry); diag lives in q0/q1.
__global__ __launch_bounds__(256) void k_loss(
    const unsigned short* __restrict__ part, const float* __restrict__ gsums,
    const int* __restrict__ counts, float* __restrict__ out, int G)
{
    __shared__ float red[256];
    int t = threadIdx.x;
    float local = 0.f;
    const int total = NCLS * 3 * QLEN;
    for (int idx = blockIdx.x * blockDim.x + t; idx < total; idx += gridDim.x * blockDim.x) {
        int c = idx / (3 * QLEN);
        int rem = idx - c * (3 * QLEN);
        int q = rem >> 14;
        int ij = rem & (QLEN - 1);
        int il = ij >> 7, jl = ij & 127;
        int gi = il + ((q == 1) ? 128 : 0);
        int gj = jl + ((q == 0) ? 0 : 128);
        const unsigned short* p = part + ((size_t)((c * 3 + q) * G)) * QLEN + ij;
        float s = 0.f;
        for (int g = 0; g < G; ++g) s += bf2f(p[(size_t)g * QLEN]);
        float n  = (float)counts[c];
        float mi = gsums[c * D + gi] / n;
        float mj = gsums[c * D + gj] / n;
        float cov = (s - n * mi * mj) / (n - 1.f);
        float contrib;
        if (q == 2) {
            contrib = 2.f * cov * cov * (1.f / (float)D);
        } else if (il == jl) {
            float sd = sqrtf(cov + EPSF);
            contrib = fmaxf(1.f - sd, 0.f) * (1.f / (float)D);
        } else {
            contrib = cov * cov * (1.f / (float)D);
        }
        local += contrib;
    }
    red[t] = local;
    __syncthreads();
    for (int s = 128; s > 0; s >>= 1) {
        if (t < s) red[t] += red[t + s];
        __syncthreads();
    }
    if (t == 0) atomicAdd(out, red[0]);
}

// ---------------------------------------------------------------------------
extern "C" void kernel_launch(void* const* d_in, const int* in_sizes, int n_in,
                              void* d_out, int out_size, void* d_ws, size_t ws_size,
                              hipStream_t stream)
{
    const float* X      = (const float*)d_in[0];
    const int*   labels = (const int*)d_in[1];
    int nfeat = in_sizes[0];
    int nlab  = in_sizes[1];
    int nrows = nfeat / D;            // 131072
    int vfac  = nrows / nlab;         // 2 views per sample

    char* ws = (char*)d_ws;
    size_t off_sorted = 0;
    size_t sz_sorted  = (size_t)nrows * D * 2;            // 67.11 MB
    size_t off_rank   = (off_sorted + sz_sorted + 255) & ~(size_t)255;
    size_t sz_rank    = (size_t)nrows * 4;                // 524 KB
    size_t off_gs     = (off_rank + sz_rank + 255) & ~(size_t)255;
    size_t sz_gs      = (size_t)NCLS * D * 4;             // 8 KB
    size_t off_cnt    = (off_gs + sz_gs + 255) & ~(size_t)255;
    size_t off_ofs    = off_cnt + 64;
    size_t off_cur    = off_ofs + 64;
    size_t off_part   = (off_cur + 64 + 255) & ~(size_t)255;

    // G slab-groups per (class, quadrant), sized from actual ws_size
    size_t slab_bytes = (size_t)QLEN * 2;                 // 32 KB
    long long avail = (long long)ws_size - (long long)off_part;
    int G = (int)(avail / (long long)(3 * NCLS * slab_bytes));
    if (G > 32) G = 32;
    if (G < 1)  G = 1;                                    // ws >= 79MB proven

    unsigned short* sorted  = (unsigned short*)(ws + off_sorted);
    int*            rank    = (int*)(ws + off_rank);
    float*          gsums   = (float*)(ws + off_gs);
    int*            counts  = (int*)(ws + off_cnt);
    int*            offsets = (int*)(ws + off_ofs);
    int*            cursor  = (int*)(ws + off_cur);
    unsigned short* part    = (unsigned short*)(ws + off_part);

    hipMemsetAsync(counts, 0, 64, stream);
    hipMemsetAsync(gsums, 0, sz_gs, stream);
    hipMemsetAsync(d_out, 0, (size_t)out_size * sizeof(float), stream);

    k_hist<<<64, 256, 0, stream>>>(labels, nlab, vfac, counts);
    k_offsets<<<1, 64, 0, stream>>>(counts, offsets, cursor);
    k_rank<<<(nrows + SEG - 1) / SEG, SEG, 0, stream>>>(labels, nrows, vfac, cursor, rank);
    k_scatter<<<(nrows + 511) / 512, 512, 0, stream>>>(
        X, labels, rank, nrows, vfac, sorted, gsums);
    k_gram<<<NCLS * 3 * G, 512, 0, stream>>>(sorted, counts, offsets, part, G);
    k_loss<<<512, 256, 0, stream>>>(part, gsums, counts, (float*)d_out, G);
}

// Round 15
// 230.995 us; speedup vs baseline: 1.3338x; 1.3338x over previous
//
#include <hip/hip_runtime.h>
#include <stdint.h>

// ---------------------------------------------------------------------------
// VarianceMaximizationCovarianceMinimizationLoss on MI355X
//   features [65536,2,256] fp32, labels [65536] int32 -> scalar fp32 loss
// Round 15: BARRIER-FREE Gram. Rounds 5-14 proved ~6us per barrier-locked
//   LDS tile regardless of structure. k_gram now loads MFMA fragments
//   directly from global row-major sorted bf16 (8 imm-offset ushort loads
//   per fragment), zero LDS, zero __syncthreads -> independent waves, TLP
//   latency hiding. Classes padded to CHUNK multiples (tails zeroed) so the
//   hot loop is branch-free.
// ---------------------------------------------------------------------------

#define NCLS  8
#define D     256
#define CHUNK 1024
#define SEG   256
#define EPSF  1e-4f
#define QLEN  16384      // 128x128 slab elements
#define GMAX  16

typedef __bf16 bf16x8 __attribute__((ext_vector_type(8)));
typedef float  f32x4  __attribute__((ext_vector_type(4)));

__device__ __forceinline__ unsigned short f2bf(float f) {
    unsigned int x = __float_as_uint(f);
    x += 0x7fffu + ((x >> 16) & 1u);      // round-to-nearest-even
    return (unsigned short)(x >> 16);
}
__device__ __forceinline__ float bf2f(unsigned short u) {
    return __uint_as_float(((unsigned int)u) << 16);
}
// fragment: 8 consecutive k-rows (512B stride) at one feature column.
// p[j*256] -> byte offsets 0..3584, all immediate-offset loads.
__device__ __forceinline__ bf16x8 ld_frag(const unsigned short* __restrict__ p) {
    unsigned int w0 = (unsigned int)p[0]    | ((unsigned int)p[256]  << 16);
    unsigned int w1 = (unsigned int)p[512]  | ((unsigned int)p[768]  << 16);
    unsigned int w2 = (unsigned int)p[1024] | ((unsigned int)p[1280] << 16);
    unsigned int w3 = (unsigned int)p[1536] | ((unsigned int)p[1792] << 16);
    return __builtin_bit_cast(bf16x8, make_uint4(w0, w1, w2, w3));
}

// ---- k1a: histogram -------------------------------------------------------
__global__ void k_hist(const int* __restrict__ labels, int nlab, int vfac,
                       int* __restrict__ counts) {
    __shared__ int lc[NCLS];
    int t = threadIdx.x;
    if (t < NCLS) lc[t] = 0;
    __syncthreads();
    for (int i = blockIdx.x * blockDim.x + t; i < nlab; i += gridDim.x * blockDim.x)
        atomicAdd(&lc[labels[i] & 7], vfac);
    __syncthreads();
    if (t < NCLS && lc[t]) atomicAdd(&counts[t], lc[t]);
}

// ---- k1b: PADDED offsets (each class region a CHUNK multiple) + cursors ---
__global__ void k_offsets(const int* __restrict__ counts,
                          int* __restrict__ offsets, int* __restrict__ cursor) {
    if (threadIdx.x == 0) {
        int acc = 0;
        for (int c = 0; c < NCLS; ++c) {
            offsets[c] = acc;
            cursor[c] = acc;
            int nch = (counts[c] + CHUNK - 1) / CHUNK;
            acc += nch * CHUNK;
        }
    }
}

// ---- k2: inverse permutation rank[row] = padded sorted position -----------
__global__ __launch_bounds__(256) void k_rank(
    const int* __restrict__ labels, int nrows, int vfac,
    int* __restrict__ cursor, int* __restrict__ rank)
{
    __shared__ int lcnt[NCLS], lbase[NCLS];
    int t = threadIdx.x;
    int row = blockIdx.x * SEG + t;
    if (t < NCLS) lcnt[t] = 0;
    __syncthreads();
    int c = 0, rk = 0;
    bool ok = (row < nrows);
    if (ok) {
        c = labels[row / vfac] & 7;
        rk = atomicAdd(&lcnt[c], 1);
    }
    __syncthreads();
    if (t < NCLS) lbase[t] = lcnt[t] ? atomicAdd(&cursor[t], lcnt[t]) : 0;
    __syncthreads();
    if (ok) rank[row] = lbase[c] + rk;
}

// ---- k2b: zero the padded tail rows of each class region ------------------
__global__ __launch_bounds__(256) void k_ztail(
    const int* __restrict__ counts, const int* __restrict__ offsets,
    unsigned short* __restrict__ sorted)
{
    int c = blockIdx.x;
    int n = counts[c];
    int nch = (n + CHUNK - 1) / CHUNK;
    int rows_t = nch * CHUNK - n;
    if (rows_t <= 0) return;
    uint4* base = (uint4*)(sorted + (((size_t)(offsets[c] + n)) << 8));
    int total = rows_t * 64;              // 64 x 16B per 512B row
    const uint4 z = make_uint4(0u, 0u, 0u, 0u);
    for (int i = threadIdx.x; i < total; i += blockDim.x) base[i] = z;
}

// ---- k3: linear-read scatter to padded sorted bf16 + fused class sums -----
// (round-14 form, passed: consistent [w][c][e][lane] sumbuf strides)
__global__ __launch_bounds__(512) void k_scatter(
    const float* __restrict__ X, const int* __restrict__ labels,
    const int* __restrict__ rank, int nrows, int vfac,
    unsigned short* __restrict__ sorted, float* __restrict__ gsums)
{
    __shared__ float sumbuf[8][NCLS][4][64];        // 64 KB
    int t = threadIdx.x;
    int w = t >> 6, lane = t & 63;

    for (int i = t; i < 8 * NCLS * 4 * 64; i += 512)
        (&sumbuf[0][0][0][0])[i] = 0.f;
    __syncthreads();

    int r0w = blockIdx.x * 512 + w * 64;
    if (r0w < nrows) {
        int myrow = r0w + lane;
        int rankv = (myrow < nrows) ? rank[myrow] : 0;
        int labv  = (myrow < nrows) ? (labels[myrow / vfac] & 7) : 0;
        int nloc = min(64, nrows - r0w);
        for (int i = 0; i < nloc; ++i) {
            int dest = __shfl(rankv, i, 64);
            int c    = __shfl(labv, i, 64);
            f32x4 v = *(const f32x4*)(X + ((size_t)(r0w + i) << 8) + lane * 4);
            float* sc = &sumbuf[w][c][0][lane];     // +64 per e
            sc[0]   += v[0];
            sc[64]  += v[1];
            sc[128] += v[2];
            sc[192] += v[3];
            ushort4 o;
            o.x = f2bf(v[0]); o.y = f2bf(v[1]); o.z = f2bf(v[2]); o.w = f2bf(v[3]);
            *(ushort4*)(sorted + ((size_t)dest << 8) + lane * 4) = o;
        }
    }
    __syncthreads();

    for (int s = t; s < NCLS * 4 * 64; s += 512) {
        float val = 0.f;
        #pragma unroll
        for (int wb = 0; wb < 8; ++wb)
            val += (&sumbuf[0][0][0][0])[wb * (NCLS * 4 * 64) + s];
        if (val != 0.f) {
            int c  = s >> 8;
            int e  = (s >> 6) & 3;
            int ln = s & 63;
            atomicAdd(&gsums[c * D + ln * 4 + e], val);
        }
    }
}

// ---- k4: barrier-free per-(class, quadrant, g) 128x128 Gram ---------------
// WG = 512 threads (8 waves as 2 wr x 4 wc; wave = 64 rows x 32 cols,
// acc 4x2 = 32 AGPR). NO LDS, NO barriers: fragments assembled directly
// from global sorted (8 imm-offset ushort loads each; feat-contiguous
// lines -> L1 reuse across lanes/ti). Padded regions -> no bounds checks.
__global__ __launch_bounds__(512) void k_gram(
    const unsigned short* __restrict__ sorted,
    const int* __restrict__ counts, const int* __restrict__ offsets,
    unsigned short* __restrict__ part, int G)
{
    int t = threadIdx.x;
    int lane = t & 63;
    int w = t >> 6;
    int wr = w >> 2, wc = w & 3;

    int blk = blockIdx.x;
    int c = blk / (3 * G);
    int rem = blk - c * (3 * G);
    int q = rem / G;
    int g = rem - q * G;

    int poff = offsets[c];
    int n = counts[c];
    int nch = (n + CHUNK - 1) / CHUNK;

    int rowb = (q == 1) ? 128 : 0;      // A-side global feature base
    int colb = (q == 0) ? 0 : 128;      // B-side global feature base

    int feat_a0 = rowb + wr * 64 + (lane & 15);
    int feat_b0 = colb + wc * 32 + (lane & 15);
    int kh = (lane >> 4) * 8;

    f32x4 acc[4][2];
    #pragma unroll
    for (int i = 0; i < 4; ++i)
        #pragma unroll
        for (int j = 0; j < 2; ++j)
            #pragma unroll
            for (int r = 0; r < 4; ++r) acc[i][j][r] = 0.f;

    for (int m = g; m < nch; m += G) {
        const unsigned short* cb = sorted + (((size_t)(poff + m * CHUNK)) << 8);
        #pragma unroll 1
        for (int ks = 0; ks < CHUNK / 32; ++ks) {
            const unsigned short* pk = cb + (((size_t)(ks * 32 + kh)) << 8);
            bf16x8 afr[4], bfr[2];
            #pragma unroll
            for (int ti = 0; ti < 4; ++ti)
                afr[ti] = ld_frag(pk + feat_a0 + ti * 16);
            #pragma unroll
            for (int tj = 0; tj < 2; ++tj)
                bfr[tj] = ld_frag(pk + feat_b0 + tj * 16);
            #pragma unroll
            for (int ti = 0; ti < 4; ++ti)
                #pragma unroll
                for (int tj = 0; tj < 2; ++tj)
                    acc[ti][tj] = __builtin_amdgcn_mfma_f32_16x16x32_bf16(
                        afr[ti], bfr[tj], acc[ti][tj], 0, 0, 0);
        }
    }

    // flush 128x128 bf16 slab (C/D: col=lane&15, row=(lane>>4)*4+r)
    unsigned short* dst = part + (size_t)blk * QLEN;
    #pragma unroll
    for (int ti = 0; ti < 4; ++ti) {
        int row0 = wr * 64 + ti * 16 + ((lane >> 4) << 2);
        #pragma unroll
        for (int tj = 0; tj < 2; ++tj) {
            int col = wc * 32 + tj * 16 + (lane & 15);
            #pragma unroll
            for (int r = 0; r < 4; ++r)
                dst[(row0 + r) * 128 + col] = f2bf(acc[ti][tj][r]);
        }
    }
}

// ---- k5: loss epilogue from (c,q,g) bf16 slabs ----------------------------
// full-matrix sums = q0 + q1 + 2*q2 (symmetry); diag lives in q0/q1.
__global__ __launch_bounds__(256) void k_loss(
    const unsigned short* __restrict__ part, const float* __restrict__ gsums,
    const int* __restrict__ counts, float* __restrict__ out, int G)
{
    __shared__ float red[256];
    int t = threadIdx.x;
    float local = 0.f;
    const int total = NCLS * 3 * QLEN;
    for (int idx = blockIdx.x * blockDim.x + t; idx < total; idx += gridDim.x * blockDim.x) {
        int c = idx / (3 * QLEN);
        int rem = idx - c * (3 * QLEN);
        int q = rem >> 14;
        int ij = rem & (QLEN - 1);
        int il = ij >> 7, jl = ij & 127;
        int gi = il + ((q == 1) ? 128 : 0);
        int gj = jl + ((q == 0) ? 0 : 128);
        const unsigned short* p = part + ((size_t)((c * 3 + q) * G)) * QLEN + ij;
        float s = 0.f;
        for (int g = 0; g < G; ++g) s += bf2f(p[(size_t)g * QLEN]);
        float n  = (float)counts[c];
        float mi = gsums[c * D + gi] / n;
        float mj = gsums[c * D + gj] / n;
        float cov = (s - n * mi * mj) / (n - 1.f);
        float contrib;
        if (q == 2) {
            contrib = 2.f * cov * cov * (1.f / (float)D);
        } else if (il == jl) {
            float sd = sqrtf(cov + EPSF);
            contrib = fmaxf(1.f - sd, 0.f) * (1.f / (float)D);
        } else {
            contrib = cov * cov * (1.f / (float)D);
        }
        local += contrib;
    }
    red[t] = local;
    __syncthreads();
    for (int s = 128; s > 0; s >>= 1) {
        if (t < s) red[t] += red[t + s];
        __syncthreads();
    }
    if (t == 0) atomicAdd(out, red[0]);
}

// ---------------------------------------------------------------------------
extern "C" void kernel_launch(void* const* d_in, const int* in_sizes, int n_in,
                              void* d_out, int out_size, void* d_ws, size_t ws_size,
                              hipStream_t stream)
{
    const float* X      = (const float*)d_in[0];
    const int*   labels = (const int*)d_in[1];
    int nfeat = in_sizes[0];
    int nlab  = in_sizes[1];
    int nrows = nfeat / D;            // 131072
    int vfac  = nrows / nlab;         // 2 views per sample

    char* ws = (char*)d_ws;
    // padded sorted: worst case nrows + NCLS*CHUNK rows
    size_t trows      = (size_t)nrows + (size_t)NCLS * CHUNK;
    size_t off_sorted = 0;
    size_t sz_sorted  = trows * D * 2;                    // 71.3 MB
    size_t off_rank   = (off_sorted + sz_sorted + 255) & ~(size_t)255;
    size_t sz_rank    = (size_t)nrows * 4;                // 524 KB
    size_t off_gs     = (off_rank + sz_rank + 255) & ~(size_t)255;
    size_t sz_gs      = (size_t)NCLS * D * 4;             // 8 KB
    size_t off_cnt    = (off_gs + sz_gs + 255) & ~(size_t)255;
    size_t off_ofs    = off_cnt + 64;
    size_t off_cur    = off_ofs + 64;
    size_t off_part   = (off_cur + 64 + 255) & ~(size_t)255;

    // G slab-groups per (class, quadrant), sized from actual ws_size
    size_t slab_bytes = (size_t)QLEN * 2;                 // 32 KB
    long long avail = (long long)ws_size - (long long)off_part;
    int G = (int)(avail / (long long)(3 * NCLS * slab_bytes));
    if (G > GMAX) G = GMAX;
    if (G < 1)  G = 1;                                    // ws >= 78.6MB proven

    unsigned short* sorted  = (unsigned short*)(ws + off_sorted);
    int*            rank    = (int*)(ws + off_rank);
    float*          gsums   = (float*)(ws + off_gs);
    int*            counts  = (int*)(ws + off_cnt);
    int*            offsets = (int*)(ws + off_ofs);
    int*            cursor  = (int*)(ws + off_cur);
    unsigned short* part    = (unsigned short*)(ws + off_part);

    hipMemsetAsync(counts, 0, 64, stream);
    hipMemsetAsync(gsums, 0, sz_gs, stream);
    hipMemsetAsync(d_out, 0, (size_t)out_size * sizeof(float), stream);

    k_hist<<<64, 256, 0, stream>>>(labels, nlab, vfac, counts);
    k_offsets<<<1, 64, 0, stream>>>(counts, offsets, cursor);
    k_rank<<<(nrows + SEG - 1) / SEG, SEG, 0, stream>>>(labels, nrows, vfac, cursor, rank);
    k_ztail<<<NCLS, 256, 0, stream>>>(counts, offsets, sorted);
    k_scatter<<<(nrows + 511) / 512, 512, 0, stream>>>(
        X, labels, rank, nrows, vfac, sorted, gsums);
    k_gram<<<NCLS * 3 * G, 512, 0, stream>>>(sorted, counts, offsets, part, G);
    k_loss<<<512, 256, 0, stream>>>(part, gsums, counts, (float*)d_out, G);
}

// Round 16
// 219.541 us; speedup vs baseline: 1.4034x; 1.0522x over previous
//
#include <hip/hip_runtime.h>
#include <stdint.h>

// ---------------------------------------------------------------------------
// VarianceMaximizationCovarianceMinimizationLoss on MI355X
//   features [65536,2,256] fp32, labels [65536] int32 -> scalar fp32 loss
// Round 16: fix the REQUEST-RATE bottleneck (r14: 64 scattered 16B segments
//   per staging instr; r15: scalar loads). k_gram staging is now perfectly
//   coalesced (16 x 64B contiguous lines per instr) using the Gram's
//   k-permutation freedom: thread t loads granule j*256+t; its 4 rows
//   {j*16 + (t&15)} become k-quad (t&15) in the PROVEN st_tile layout
//   (same permutation on A and B operands -> sum over k unchanged).
//   4-wave WGs (2-3 WG/CU), CHUNK=512, scatter atomics -> partials+reduce.
// ---------------------------------------------------------------------------

#define NCLS  8
#define D     256
#define CHUNK 512
#define SEG   256
#define EPSF  1e-4f
#define QLEN  16384      // 128x128 slab elements

typedef __bf16 bf16x8 __attribute__((ext_vector_type(8)));
typedef float  f32x4  __attribute__((ext_vector_type(4)));

__device__ __forceinline__ unsigned short f2bf(float f) {
    unsigned int x = __float_as_uint(f);
    x += 0x7fffu + ((x >> 16) & 1u);      // round-to-nearest-even
    return (unsigned short)(x >> 16);
}
__device__ __forceinline__ float bf2f(unsigned short u) {
    return __uint_as_float(((unsigned int)u) << 16);
}
// transposed + XOR-swizzled LDS write of 4 k-slots x 8 cols (layout and
// write pattern validated conflict-free rounds 3-14: SQ_LDS_BANK_CONFLICT=0)
__device__ __forceinline__ void st_tile(unsigned char* lds, const uint4* R,
                                        int kblk, int cblkg) {
    #pragma unroll
    for (int cc = 0; cc < 8; ++cc) {
        int wd = cc >> 1;
        int sh = (cc & 1) * 16;
        unsigned int e0 = (((const unsigned int*)&R[0])[wd] >> sh) & 0xffffu;
        unsigned int e1 = (((const unsigned int*)&R[1])[wd] >> sh) & 0xffffu;
        unsigned int e2 = (((const unsigned int*)&R[2])[wd] >> sh) & 0xffffu;
        unsigned int e3 = (((const unsigned int*)&R[3])[wd] >> sh) & 0xffffu;
        int ccol = cblkg * 8 + cc;
        int byt = ccol * 128 + ((kblk * 8) ^ (cc << 4));
        *(uint2*)(lds + byt) = make_uint2(e0 | (e1 << 16), e2 | (e3 << 16));
    }
}

// ---- k1a: histogram -------------------------------------------------------
__global__ void k_hist(const int* __restrict__ labels, int nlab, int vfac,
                       int* __restrict__ counts) {
    __shared__ int lc[NCLS];
    int t = threadIdx.x;
    if (t < NCLS) lc[t] = 0;
    __syncthreads();
    for (int i = blockIdx.x * blockDim.x + t; i < nlab; i += gridDim.x * blockDim.x)
        atomicAdd(&lc[labels[i] & 7], vfac);
    __syncthreads();
    if (t < NCLS && lc[t]) atomicAdd(&counts[t], lc[t]);
}

// ---- k1b: offsets + cursors ----------------------------------------------
__global__ void k_offsets(const int* __restrict__ counts,
                          int* __restrict__ offsets, int* __restrict__ cursor) {
    if (threadIdx.x == 0) {
        int acc = 0;
        for (int c = 0; c < NCLS; ++c) { offsets[c] = acc; cursor[c] = acc; acc += counts[c]; }
    }
}

// ---- k2: inverse permutation rank[row] = sorted position ------------------
__global__ __launch_bounds__(256) void k_rank(
    const int* __restrict__ labels, int nrows, int vfac,
    int* __restrict__ cursor, int* __restrict__ rank)
{
    __shared__ int lcnt[NCLS], lbase[NCLS];
    int t = threadIdx.x;
    int row = blockIdx.x * SEG + t;
    if (t < NCLS) lcnt[t] = 0;
    __syncthreads();
    int c = 0, rk = 0;
    bool ok = (row < nrows);
    if (ok) {
        c = labels[row / vfac] & 7;
        rk = atomicAdd(&lcnt[c], 1);
    }
    __syncthreads();
    if (t < NCLS) lbase[t] = lcnt[t] ? atomicAdd(&cursor[t], lcnt[t]) : 0;
    __syncthreads();
    if (ok) rank[row] = lbase[c] + rk;
}

// ---- k3: linear-read scatter to sorted bf16 + per-WG class-sum partials ---
// (round-14 proven form; atomics replaced by a coalesced partials store)
__global__ __launch_bounds__(512) void k_scatter(
    const float* __restrict__ X, const int* __restrict__ labels,
    const int* __restrict__ rank, int nrows, int vfac,
    unsigned short* __restrict__ sorted, float* __restrict__ spart)
{
    __shared__ float sumbuf[8][NCLS][4][64];        // 64 KB
    int t = threadIdx.x;
    int w = t >> 6, lane = t & 63;

    for (int i = t; i < 8 * NCLS * 4 * 64; i += 512)
        (&sumbuf[0][0][0][0])[i] = 0.f;
    __syncthreads();

    int r0w = blockIdx.x * 512 + w * 64;
    if (r0w < nrows) {
        int myrow = r0w + lane;
        int rankv = (myrow < nrows) ? rank[myrow] : 0;
        int labv  = (myrow < nrows) ? (labels[myrow / vfac] & 7) : 0;
        int nloc = min(64, nrows - r0w);
        for (int i = 0; i < nloc; ++i) {
            int dest = __shfl(rankv, i, 64);
            int c    = __shfl(labv, i, 64);
            f32x4 v = *(const f32x4*)(X + ((size_t)(r0w + i) << 8) + lane * 4);
            float* sc = &sumbuf[w][c][0][lane];     // +64 per e
            sc[0]   += v[0];
            sc[64]  += v[1];
            sc[128] += v[2];
            sc[192] += v[3];
            ushort4 o;
            o.x = f2bf(v[0]); o.y = f2bf(v[1]); o.z = f2bf(v[2]); o.w = f2bf(v[3]);
            *(ushort4*)(sorted + ((size_t)dest << 8) + lane * 4) = o;
        }
    }
    __syncthreads();

    // merge the 8 wave regions, store per-WG partials (coalesced, no atomics)
    float* dst = spart + (size_t)blockIdx.x * (NCLS * 4 * 64);
    for (int s = t; s < NCLS * 4 * 64; s += 512) {
        float val = 0.f;
        #pragma unroll
        for (int wb = 0; wb < 8; ++wb)
            val += (&sumbuf[0][0][0][0])[wb * (NCLS * 4 * 64) + s];
        dst[s] = val;
    }
}

// ---- k3b: reduce scatter partials -> per-class feature sums ---------------
__global__ __launch_bounds__(256) void k_gsum(
    const float* __restrict__ spart, int nwg, float* __restrict__ gsums)
{
    int c = blockIdx.x;
    int d = threadIdx.x;                 // 0..255 feature index
    int e = d & 3, lane = d >> 2;
    float s = 0.f;
    for (int wg = 0; wg < nwg; ++wg)
        s += spart[(size_t)wg * (NCLS * 256) + c * 256 + e * 64 + lane];
    gsums[c * D + d] = s;
}

// ---- k4: per-(class, quadrant, g) 128x128 Gram, COALESCED staging ---------
// WG = 256 threads (4 waves as 2x2: wave = 64x64, acc 4x4 = 64 AGPR).
// Quadrants: q0=[0:128]x[0:128], q1=[128:]x[128:], q2=[0:128]x[128:].
// Staging (q0/q1, 16KB = 64 rows x 128 feats): instr j loads granule
//   g = j*256 + t: row = j*16 + (t&15), 16B feats at (t>>4)*16B -- per
//   instruction the wave covers 16 rows x 64B = 16 contiguous 64B lines.
// k-permutation: row j*16+m <-> k-slot 4m+j (m=t&15); same permutation on
// A and B fragments -> Gram sum unchanged. st_tile(kblk=t&15,...) is the
// round-14-proven conflict-free write pattern.
__global__ __launch_bounds__(256) void k_gram(
    const unsigned short* __restrict__ sorted,
    const int* __restrict__ counts, const int* __restrict__ offsets,
    unsigned short* __restrict__ part, int G)
{
    __shared__ __align__(16) unsigned char lds[64 * 256 * 2];   // 32 KB

    int t = threadIdx.x;
    int lane = t & 63;
    int w = t >> 6;
    int wr = w >> 1, wc = w & 1;

    int blk = blockIdx.x;
    int c = blk / (3 * G);
    int rem = blk - c * (3 * G);
    int q = rem / G;
    int g = rem - q * G;

    int base0 = offsets[c];
    int n = counts[c];
    int nch = (n + CHUNK - 1) / CHUNK;

    int colb = (q == 1) ? 128 : 0;      // staged global feat base (q2: 0..255)
    bool two = (q == 2);
    int bbase = two ? 128 : 0;          // B-fragment local col base

    f32x4 acc[4][4];
    #pragma unroll
    for (int i = 0; i < 4; ++i)
        #pragma unroll
        for (int j = 0; j < 4; ++j)
            #pragma unroll
            for (int r = 0; r < 4; ++r) acc[i][j][r] = 0.f;

    const uint4 zq = make_uint4(0u, 0u, 0u, 0u);

    for (int m = g; m < nch; m += G) {
        int base = base0 + m * CHUNK;
        int rows = min(CHUNK, n - m * CHUNK);
        int ntiles = (rows + 63) >> 6;
        for (int kt = 0; kt < ntiles; ++kt) {
            uint4 R[4], R2[4];
            if (!two) {
                // 16KB: row = j*16 + (t&15), 16B col (t>>4)
                int mq = t & 15, gc = t >> 4;
                #pragma unroll
                for (int j = 0; j < 4; ++j) {
                    int r = kt * 64 + j * 16 + mq;
                    const unsigned short* p = sorted
                        + (size_t)(base + min(r, rows - 1)) * 256 + colb + gc * 8;
                    R[j] = (r < rows) ? *(const uint4*)p : zq;
                }
            } else {
                // 32KB: row = j*8 + (t&7) (+32 for batch 2), 16B col (t>>3)
                int mq = t & 7, gc = t >> 3;
                #pragma unroll
                for (int j = 0; j < 4; ++j) {
                    int r = kt * 64 + j * 8 + mq;
                    const unsigned short* p = sorted
                        + (size_t)(base + min(r, rows - 1)) * 256 + gc * 8;
                    R[j] = (r < rows) ? *(const uint4*)p : zq;
                    int r2 = r + 32;
                    const unsigned short* p2 = sorted
                        + (size_t)(base + min(r2, rows - 1)) * 256 + gc * 8;
                    R2[j] = (r2 < rows) ? *(const uint4*)p2 : zq;
                }
            }
            __syncthreads();            // previous tile's LDS reads done
            if (!two) {
                st_tile(lds, R, t & 15, t >> 4);
            } else {
                st_tile(lds, R, t & 7, t >> 3);
                st_tile(lds, R2, 8 + (t & 7), t >> 3);
            }
            __syncthreads();            // staging visible
            #pragma unroll
            for (int ks = 0; ks < 2; ++ks) {
                int kb2 = ks * 64 + ((lane >> 4) << 4);
                int swz = (lane & 7) << 4;
                bf16x8 bfr[4];
                #pragma unroll
                for (int tj = 0; tj < 4; ++tj) {
                    int ccol = bbase + wc * 64 + tj * 16 + (lane & 15);
                    bfr[tj] = __builtin_bit_cast(bf16x8,
                        *(const uint4*)(lds + ccol * 128 + (kb2 ^ swz)));
                }
                #pragma unroll
                for (int ti = 0; ti < 4; ++ti) {
                    int ccol = wr * 64 + ti * 16 + (lane & 15);
                    bf16x8 af = __builtin_bit_cast(bf16x8,
                        *(const uint4*)(lds + ccol * 128 + (kb2 ^ swz)));
                    #pragma unroll
                    for (int tj = 0; tj < 4; ++tj)
                        acc[ti][tj] = __builtin_amdgcn_mfma_f32_16x16x32_bf16(
                            af, bfr[tj], acc[ti][tj], 0, 0, 0);
                }
            }
        }
    }

    // flush 128x128 bf16 slab (C/D: col=lane&15, row=(lane>>4)*4+r)
    unsigned short* dst = part + (size_t)blk * QLEN;
    #pragma unroll
    for (int ti = 0; ti < 4; ++ti) {
        int row0 = wr * 64 + ti * 16 + ((lane >> 4) << 2);
        #pragma unroll
        for (int tj = 0; tj < 4; ++tj) {
            int col = wc * 64 + tj * 16 + (lane & 15);
            #pragma unroll
            for (int r = 0; r < 4; ++r)
                dst[(row0 + r) * 128 + col] = f2bf(acc[ti][tj][r]);
        }
    }
}

// ---- k5: loss epilogue from (c,q,g) bf16 slabs ----------------------------
// full-matrix sums = q0 + q1 + 2*q2 (symmetry); diag lives in q0/q1.
__global__ __launch_bounds__(256) void k_loss(
    const unsigned short* __restrict__ part, const float* __restrict__ gsums,
    const int* __restrict__ counts, float* __restrict__ out, int G)
{
    __shared__ float red[256];
    int t = threadIdx.x;
    float local = 0.f;
    const int total = NCLS * 3 * QLEN;
    for (int idx = blockIdx.x * blockDim.x + t; idx < total; idx += gridDim.x * blockDim.x) {
        int c = idx / (3 * QLEN);
        int rem = idx - c * (3 * QLEN);
        int q = rem >> 14;
        int ij = rem & (QLEN - 1);
        int il = ij >> 7, jl = ij & 127;
        int gi = il + ((q == 1) ? 128 : 0);
        int gj = jl + ((q == 0) ? 0 : 128);
        const unsigned short* p = part + ((size_t)((c * 3 + q) * G)) * QLEN + ij;
        float s = 0.f;
        for (int g = 0; g < G; ++g) s += bf2f(p[(size_t)g * QLEN]);
        float n  = (float)counts[c];
        float mi = gsums[c * D + gi] / n;
        float mj = gsums[c * D + gj] / n;
        float cov = (s - n * mi * mj) / (n - 1.f);
        float contrib;
        if (q == 2) {
            contrib = 2.f * cov * cov * (1.f / (float)D);
        } else if (il == jl) {
            float sd = sqrtf(cov + EPSF);
            contrib = fmaxf(1.f - sd, 0.f) * (1.f / (float)D);
        } else {
            contrib = cov * cov * (1.f / (float)D);
        }
        local += contrib;
    }
    red[t] = local;
    __syncthreads();
    for (int s = 128; s > 0; s >>= 1) {
        if (t < s) red[t] += red[t + s];
        __syncthreads();
    }
    if (t == 0) atomicAdd(out, red[0]);
}

// ---------------------------------------------------------------------------
extern "C" void kernel_launch(void* const* d_in, const int* in_sizes, int n_in,
                              void* d_out, int out_size, void* d_ws, size_t ws_size,
                              hipStream_t stream)
{
    const float* X      = (const float*)d_in[0];
    const int*   labels = (const int*)d_in[1];
    int nfeat = in_sizes[0];
    int nlab  = in_sizes[1];
    int nrows = nfeat / D;            // 131072
    int vfac  = nrows / nlab;         // 2 views per sample

    int nsc = (nrows + 511) / 512;    // scatter WG count (256)

    char* ws = (char*)d_ws;
    size_t off_sorted = 0;
    size_t sz_sorted  = (size_t)nrows * D * 2;            // 67.11 MB
    size_t off_rank   = (off_sorted + sz_sorted + 255) & ~(size_t)255;
    size_t sz_rank    = (size_t)nrows * 4;                // 524 KB
    size_t off_sp     = (off_rank + sz_rank + 255) & ~(size_t)255;
    size_t sz_sp      = (size_t)nsc * NCLS * 256 * 4;     // 2 MB
    size_t off_gs     = (off_sp + sz_sp + 255) & ~(size_t)255;
    size_t sz_gs      = (size_t)NCLS * D * 4;             // 8 KB
    size_t off_cnt    = (off_gs + sz_gs + 255) & ~(size_t)255;
    size_t off_ofs    = off_cnt + 64;
    size_t off_cur    = off_ofs + 64;
    size_t off_part   = (off_cur + 64 + 255) & ~(size_t)255;

    // G slab-groups per (class, quadrant), sized from actual ws_size
    size_t slab_bytes = (size_t)QLEN * 2;                 // 32 KB bf16
    long long avail = (long long)ws_size - (long long)off_part;
    int G = (int)(avail / (long long)(3 * NCLS * slab_bytes));
    if (G > 32) G = 32;
    if (G < 1)  G = 1;

    unsigned short* sorted  = (unsigned short*)(ws + off_sorted);
    int*            rank    = (int*)(ws + off_rank);
    float*          spart   = (float*)(ws + off_sp);
    float*          gsums   = (float*)(ws + off_gs);
    int*            counts  = (int*)(ws + off_cnt);
    int*            offsets = (int*)(ws + off_ofs);
    int*            cursor  = (int*)(ws + off_cur);
    unsigned short* part    = (unsigned short*)(ws + off_part);

    hipMemsetAsync(counts, 0, 64, stream);
    hipMemsetAsync(d_out, 0, (size_t)out_size * sizeof(float), stream);

    k_hist<<<64, 256, 0, stream>>>(labels, nlab, vfac, counts);
    k_offsets<<<1, 64, 0, stream>>>(counts, offsets, cursor);
    k_rank<<<(nrows + SEG - 1) / SEG, SEG, 0, stream>>>(labels, nrows, vfac, cursor, rank);
    k_scatter<<<nsc, 512, 0, stream>>>(X, labels, rank, nrows, vfac, sorted, spart);
    k_gsum<<<NCLS, 256, 0, stream>>>(spart, nsc, gsums);
    k_gram<<<NCLS * 3 * G, 256, 0, stream>>>(sorted, counts, offsets, part, G);
    k_loss<<<512, 256, 0, stream>>>(part, gsums, counts, (float*)d_out, G);
}